// Round 1
// 421.961 us; speedup vs baseline: 1.0055x; 1.0055x over previous
//
#include <hip/hip_runtime.h>
#include <hip/hip_bf16.h>
#include <cstdint>
#include <cstddef>

typedef __bf16 bf16_t;
typedef __bf16 bf16x8 __attribute__((ext_vector_type(8)));
typedef __bf16 bf16x4 __attribute__((ext_vector_type(4)));
typedef float  f32x4  __attribute__((ext_vector_type(4)));

#define M_DIM 16384   // B*S = 4*4096
#define N_DIM 3072    // 3*O
#define K_DIM 1024    // I
#define R_DIM 256
#define O_DIM 1024

#define BM 128
#define BN 128
#define BK 32
#define NT_TILES 24          // N_DIM / BN
#define GRID_GEMM 3072       // (M/BM)*(N/BN)
#define CHUNK_XCD 384        // GRID_GEMM / 8 XCDs (3072 % 8 == 0 -> bijective)

// direct async HBM -> LDS, 16 B/lane (m97 structure: 874-912 TF at 128^2 tile
// vs 646 TF reg-staged -- learn_hip m151/m97)
__device__ __forceinline__ void gload_lds16(const bf16_t* g, bf16_t* l) {
  __builtin_amdgcn_global_load_lds(
      (__attribute__((address_space(1))) void*)(g),
      (__attribute__((address_space(3))) void*)(l), 16, 0, 0);
}

// ---------------------------------------------------------------------------
// Kernel 0 (merged): blocks [0,128)   : Q-rows of base_w fp32->bf16
//                    blocks [128,384) : K/V delta rows (VeRA) + add + bf16
//                    blocks [384,8576): x fp32 -> bf16 (16M elems, 8/thread)
// Merging removes one launch and overlaps the latency-bound delta loop with
// the BW-bound conversion.
// ---------------------------------------------------------------------------
__global__ __launch_bounds__(256) void prep_all(
    const float* __restrict__ x,       // (16384, 1024)
    const float* __restrict__ base_w,  // (3072, 1024)
    const float* __restrict__ vA,      // (256, 1024)
    const float* __restrict__ vB,      // (1024, 256)
    const float* __restrict__ vd,      // (2, 256)
    const float* __restrict__ vb,      // (2, 1024)
    bf16_t* __restrict__ Wf,           // (3072, 1024) bf16 out
    bf16_t* __restrict__ xh)           // (16384, 1024) bf16 out (may be null)
{
  const int blk = blockIdx.x;
  const int t = threadIdx.x;

  if (blk >= 384) {
    // x fp32 -> bf16, 8 contiguous elems per thread, fully coalesced
    const size_t base = ((size_t)(blk - 384) * 256 + t) * 8;
    const f32x4 v0 = *(const f32x4*)(x + base);
    const f32x4 v1 = *(const f32x4*)(x + base + 4);
    bf16x8 o;
    o[0] = (bf16_t)v0[0]; o[1] = (bf16_t)v0[1]; o[2] = (bf16_t)v0[2]; o[3] = (bf16_t)v0[3];
    o[4] = (bf16_t)v1[0]; o[5] = (bf16_t)v1[1]; o[6] = (bf16_t)v1[2]; o[7] = (bf16_t)v1[3];
    *(bf16x8*)(xh + base) = o;
    return;
  }

  if (blk < 128) {
    // convert Q rows fp32 -> bf16; thread t owns cols 4t..4t+3 of 8 rows
    const float* src = base_w + (size_t)blk * 8 * K_DIM;
    bf16_t*      dst = Wf + (size_t)blk * 8 * K_DIM;
#pragma unroll
    for (int rr = 0; rr < 8; ++rr) {
      const f32x4 v = *(const f32x4*)(src + rr * K_DIM + t * 4);
      bf16x4 ov;
      ov[0] = (bf16_t)v[0]; ov[1] = (bf16_t)v[1];
      ov[2] = (bf16_t)v[2]; ov[3] = (bf16_t)v[3];
      *(bf16x4*)(dst + rr * K_DIM + t * 4) = ov;
    }
    return;
  }

  // delta rows: delta[k][o][i] = vb[k][o] * sum_r vB[o][r]*vd[k][r]*vA[r][i]
  const int rb = (blk - 128) * 8;   // delta-local row base 0..2040
  const int k  = rb >> 10;          // 0 = K-proj, 1 = V-proj (uniform per block)
  const int ob = rb & 1023;         // o base within this k

  __shared__ float coeffT[R_DIM][8];  // [r][row-in-block], 8 KB
  {
    const int r = t;  // 256 threads == R
    const float d = vd[k * R_DIM + r];
#pragma unroll
    for (int rr = 0; rr < 8; ++rr) {
      const int o = ob + rr;
      coeffT[r][rr] = vb[k * O_DIM + o] * vB[(size_t)o * R_DIM + r] * d;
    }
  }
  __syncthreads();

  float acc[8][4];
#pragma unroll
  for (int rr = 0; rr < 8; ++rr)
#pragma unroll
    for (int c = 0; c < 4; ++c) acc[rr][c] = 0.0f;

  for (int r = 0; r < R_DIM; ++r) {
    const f32x4 av = *(const f32x4*)(vA + (size_t)r * K_DIM + t * 4);
    const f32x4 c0 = *(const f32x4*)&coeffT[r][0];
    const f32x4 c1 = *(const f32x4*)&coeffT[r][4];
#pragma unroll
    for (int rr = 0; rr < 8; ++rr) {
      const float cc = (rr < 4) ? c0[rr] : c1[rr - 4];
      acc[rr][0] += cc * av[0];
      acc[rr][1] += cc * av[1];
      acc[rr][2] += cc * av[2];
      acc[rr][3] += cc * av[3];
    }
  }

#pragma unroll
  for (int rr = 0; rr < 8; ++rr) {
    const size_t row = (size_t)(1024 + rb + rr);
    const f32x4 bw = *(const f32x4*)(base_w + row * K_DIM + t * 4);
    bf16x4 ov;
    ov[0] = (bf16_t)(bw[0] + acc[rr][0]);
    ov[1] = (bf16_t)(bw[1] + acc[rr][1]);
    ov[2] = (bf16_t)(bw[2] + acc[rr][2]);
    ov[3] = (bf16_t)(bw[3] + acc[rr][3]);
    *(bf16x4*)(Wf + row * K_DIM + t * 4) = ov;
  }
}

// ---------------------------------------------------------------------------
// Kernel 1: out(fp32) = X @ Wf^T + bias  (bf16 MFMA GEMM, B^T weights)
// m97 structure: 128x128 tile, BK=32, 4 waves (2x2), 4x4 16x16x32 frags/wave,
// staging via global_load_lds width=16 (async HBM->LDS, no VGPR round-trip),
// single LDS buffer, 2 barriers / K-step. + XCD-aware block swizzle (T1).
// PRECONV=false fallback: reg-stage A from fp32 with inline convert.
// ---------------------------------------------------------------------------
template <bool PRECONV>
__global__ __launch_bounds__(256) void gemm_qkv(
    const bf16_t* __restrict__ Xh,    // (16384, 1024) bf16 (PRECONV)
    const float*  __restrict__ Xf,    // (16384, 1024) fp32 (!PRECONV)
    const bf16_t* __restrict__ W,     // (3072, 1024)  bf16 row-major (N,K)
    const float*  __restrict__ bias,  // (3072,) fp32
    float* __restrict__ out)          // (16384, 3072) fp32
{
  __shared__ bf16_t As[BM * BK];  // 8 KB, row-major, row stride BK
  __shared__ bf16_t Bs[BN * BK];  // 8 KB

  // XCD swizzle: blockIdx round-robins XCDs (bid&7 = xcd); give each XCD a
  // contiguous chunk of logical tiles so neighbor tiles share L2 panels.
  const int rawbid = blockIdx.x;
  const int bid = (rawbid & 7) * CHUNK_XCD + (rawbid >> 3);
  const int nt = bid % NT_TILES;
  const int mt = bid / NT_TILES;
  const int m0 = mt * BM;
  const int n0 = nt * BN;

  const int t = threadIdx.x;
  const int lane = t & 63;
  const int w = t >> 6;          // wave 0..3
  const int wm = w >> 1;         // wave row 0..1
  const int wn = w & 1;          // wave col 0..1

  // staging coords: thread t -> tile row r0 (and r0+64), 16B chunk c0.
  // LDS byte addr = 16*t (+4KB for the second load): linear in lane order,
  // exactly the wave-uniform-base + lane*16 pattern global_load_lds writes.
  const int r0 = t >> 2;          // 0..63
  const int c0 = (t & 3) * 8;     // elem offset 0,8,16,24

  const bf16_t* gB0 = W + (size_t)(n0 + r0) * K_DIM + c0;
  const bf16_t* gB1 = gB0 + (size_t)64 * K_DIM;
  bf16_t* lA0 = As + r0 * BK + c0;
  bf16_t* lA1 = As + (r0 + 64) * BK + c0;
  bf16_t* lB0 = Bs + r0 * BK + c0;
  bf16_t* lB1 = Bs + (r0 + 64) * BK + c0;

  const bf16_t* gA0h = nullptr; const bf16_t* gA1h = nullptr;
  const float*  gA0f = nullptr; const float*  gA1f = nullptr;
  if constexpr (PRECONV) {
    gA0h = Xh + (size_t)(m0 + r0) * K_DIM + c0;
    gA1h = gA0h + (size_t)64 * K_DIM;
  } else {
    gA0f = Xf + (size_t)(m0 + r0) * K_DIM + c0;
    gA1f = gA0f + (size_t)64 * K_DIM;
  }

  const f32x4 zero4 = {0.0f, 0.0f, 0.0f, 0.0f};
  f32x4 acc[4][4];
#pragma unroll
  for (int i = 0; i < 4; ++i)
#pragma unroll
    for (int j = 0; j < 4; ++j) acc[i][j] = zero4;

  // fragment read coords (m89/m91-verified gemm_bt layout):
  // own-row = lane&15, k = (lane>>4)*8 + j  -> 16B contiguous ds_read_b128
  const int row_a = wm * 64 + (lane & 15);
  const int row_b = wn * 64 + (lane & 15);
  const int kb = (lane >> 4) * 8;

  for (int k0 = 0; k0 < K_DIM; k0 += BK) {
    if constexpr (PRECONV) {
      gload_lds16(gA0h + k0, lA0);
      gload_lds16(gA1h + k0, lA1);
    } else {
      const f32x4 u0 = *(const f32x4*)(gA0f + k0);
      const f32x4 u1 = *(const f32x4*)(gA0f + k0 + 4);
      const f32x4 u2 = *(const f32x4*)(gA1f + k0);
      const f32x4 u3 = *(const f32x4*)(gA1f + k0 + 4);
      bf16x8 a0, a1;
#pragma unroll
      for (int c = 0; c < 4; ++c) {
        a0[c] = (bf16_t)u0[c]; a0[c + 4] = (bf16_t)u1[c];
        a1[c] = (bf16_t)u2[c]; a1[c + 4] = (bf16_t)u3[c];
      }
      *(bf16x8*)lA0 = a0;
      *(bf16x8*)lA1 = a1;
    }
    gload_lds16(gB0 + k0, lB0);
    gload_lds16(gB1 + k0, lB1);
    __syncthreads();  // compiler drains vmcnt(0) here -> LDS tile complete

    bf16x8 a[4], b[4];
#pragma unroll
    for (int i = 0; i < 4; ++i)
      a[i] = *(const bf16x8*)(As + (row_a + i * 16) * BK + kb);
#pragma unroll
    for (int j = 0; j < 4; ++j)
      b[j] = *(const bf16x8*)(Bs + (row_b + j * 16) * BK + kb);

#pragma unroll
    for (int i = 0; i < 4; ++i)
#pragma unroll
      for (int j = 0; j < 4; ++j)
        acc[i][j] = __builtin_amdgcn_mfma_f32_16x16x32_bf16(a[i], b[j], acc[i][j], 0, 0, 0);

    __syncthreads();  // protect LDS before next iteration's staging
  }

  // epilogue: C/D layout col = lane&15 (n), row = (lane>>4)*4 + reg (m)
  const int colg = lane & 15;
  const int rq = (lane >> 4) * 4;
#pragma unroll
  for (int j = 0; j < 4; ++j) {
    const int n = n0 + wn * 64 + j * 16 + colg;
    const float bv = bias[n];
#pragma unroll
    for (int i = 0; i < 4; ++i) {
      const size_t mb = (size_t)(m0 + wm * 64 + i * 16 + rq);
#pragma unroll
      for (int r = 0; r < 4; ++r)
        out[(mb + r) * N_DIM + n] = acc[i][j][r] + bv;
    }
  }
}

extern "C" void kernel_launch(void* const* d_in, const int* in_sizes, int n_in,
                              void* d_out, int out_size, void* d_ws, size_t ws_size,
                              hipStream_t stream) {
  const float* x      = (const float*)d_in[0];  // (4,4096,1024) fp32
  const float* base_w = (const float*)d_in[1];  // (3072,1024) fp32
  const float* base_b = (const float*)d_in[2];  // (3072,) fp32
  const float* vA     = (const float*)d_in[3];  // (256,1024) fp32
  const float* vB     = (const float*)d_in[4];  // (1024,256) fp32
  const float* vd     = (const float*)d_in[5];  // (2,256) fp32
  const float* vb     = (const float*)d_in[6];  // (2,1024) fp32
  float* out = (float*)d_out;                   // (16384,3072) fp32

  const size_t xh_off   = 8u * 1024 * 1024;                        // aligned 8 MB
  const size_t xh_bytes = (size_t)M_DIM * K_DIM * sizeof(bf16_t);  // 33.5 MB

  bf16_t* Wf = (bf16_t*)d_ws;
  const bool preconv = ws_size >= xh_off + xh_bytes;
  bf16_t* Xh = preconv ? (bf16_t*)((char*)d_ws + xh_off) : nullptr;

  // merged prep: 384 weight blocks + (preconv ? 8192 x-convert blocks : 0)
  prep_all<<<preconv ? 8576 : 384, 256, 0, stream>>>(x, base_w, vA, vB, vd, vb, Wf, Xh);

  if (preconv)
    gemm_qkv<true><<<GRID_GEMM, 256, 0, stream>>>(Xh, nullptr, Wf, base_b, out);
  else
    gemm_qkv<false><<<GRID_GEMM, 256, 0, stream>>>(nullptr, x, Wf, base_b, out);
}

// Round 3
// 412.025 us; speedup vs baseline: 1.0297x; 1.0241x over previous
//
#include <hip/hip_runtime.h>
#include <hip/hip_bf16.h>
#include <cstdint>
#include <cstddef>

typedef __bf16 bf16_t;
typedef __bf16 bf16x8 __attribute__((ext_vector_type(8)));
typedef __bf16 bf16x4 __attribute__((ext_vector_type(4)));
typedef float  f32x4  __attribute__((ext_vector_type(4)));

#define M_DIM 16384   // B*S
#define N_DIM 3072    // 3*O
#define K_DIM 1024    // I
#define R_DIM 256
#define O_DIM 1024

// 256^2 8-phase geometry
#define BM 256
#define BN 256
#define BK 64
#define NTILE (N_DIM / BN)                    // 12
#define GRID_GEMM ((M_DIM / BM) * NTILE)      // 768
#define CHUNK_XCD (GRID_GEMM / 8)             // 96 (768 % 8 == 0 -> bijective)
#define SMEM_BYTES 131072

// LDS region map (bf16 elems): [c][A/B][kh] -> 256 rows x 32 k, 16 KB each.
#define REGN(c, isB, kh) ((c) * 32768 + (isB) * 16384 + (kh) * 8192)

__device__ __forceinline__ void gload_lds16(const bf16_t* g, bf16_t* l) {
  __builtin_amdgcn_global_load_lds(
      (__attribute__((address_space(1))) void*)(g),
      (__attribute__((address_space(3))) void*)(l), 16, 0, 0);
}

// ---------------------------------------------------------------------------
// prep: blocks [0,128): Q-rows fp32->bf16; [128,384): VeRA delta rows;
//       [384,8576): x fp32 -> bf16  (unchanged, verified rounds 0-1)
// ---------------------------------------------------------------------------
__global__ __launch_bounds__(256) void prep_all(
    const float* __restrict__ x,
    const float* __restrict__ base_w,
    const float* __restrict__ vA,
    const float* __restrict__ vB,
    const float* __restrict__ vd,
    const float* __restrict__ vb,
    bf16_t* __restrict__ Wf,
    bf16_t* __restrict__ xh)
{
  const int blk = blockIdx.x;
  const int t = threadIdx.x;

  if (blk >= 384) {
    const size_t base = ((size_t)(blk - 384) * 256 + t) * 8;
    const f32x4 v0 = *(const f32x4*)(x + base);
    const f32x4 v1 = *(const f32x4*)(x + base + 4);
    bf16x8 o;
    o[0] = (bf16_t)v0[0]; o[1] = (bf16_t)v0[1]; o[2] = (bf16_t)v0[2]; o[3] = (bf16_t)v0[3];
    o[4] = (bf16_t)v1[0]; o[5] = (bf16_t)v1[1]; o[6] = (bf16_t)v1[2]; o[7] = (bf16_t)v1[3];
    *(bf16x8*)(xh + base) = o;
    return;
  }

  if (blk < 128) {
    const float* src = base_w + (size_t)blk * 8 * K_DIM;
    bf16_t*      dst = Wf + (size_t)blk * 8 * K_DIM;
#pragma unroll
    for (int rr = 0; rr < 8; ++rr) {
      const f32x4 v = *(const f32x4*)(src + rr * K_DIM + t * 4);
      bf16x4 ov;
      ov[0] = (bf16_t)v[0]; ov[1] = (bf16_t)v[1];
      ov[2] = (bf16_t)v[2]; ov[3] = (bf16_t)v[3];
      *(bf16x4*)(dst + rr * K_DIM + t * 4) = ov;
    }
    return;
  }

  const int rb = (blk - 128) * 8;
  const int k  = rb >> 10;
  const int ob = rb & 1023;

  __shared__ float coeffT[R_DIM][8];
  {
    const int r = t;
    const float d = vd[k * R_DIM + r];
#pragma unroll
    for (int rr = 0; rr < 8; ++rr) {
      const int o = ob + rr;
      coeffT[r][rr] = vb[k * O_DIM + o] * vB[(size_t)o * R_DIM + r] * d;
    }
  }
  __syncthreads();

  float acc[8][4];
#pragma unroll
  for (int rr = 0; rr < 8; ++rr)
#pragma unroll
    for (int c = 0; c < 4; ++c) acc[rr][c] = 0.0f;

  for (int r = 0; r < R_DIM; ++r) {
    const f32x4 av = *(const f32x4*)(vA + (size_t)r * K_DIM + t * 4);
    const f32x4 c0 = *(const f32x4*)&coeffT[r][0];
    const f32x4 c1 = *(const f32x4*)&coeffT[r][4];
#pragma unroll
    for (int rr = 0; rr < 8; ++rr) {
      const float cc = (rr < 4) ? c0[rr] : c1[rr - 4];
      acc[rr][0] += cc * av[0];
      acc[rr][1] += cc * av[1];
      acc[rr][2] += cc * av[2];
      acc[rr][3] += cc * av[3];
    }
  }

#pragma unroll
  for (int rr = 0; rr < 8; ++rr) {
    const size_t row = (size_t)(1024 + rb + rr);
    const f32x4 bw = *(const f32x4*)(base_w + row * K_DIM + t * 4);
    bf16x4 ov;
    ov[0] = (bf16_t)(bw[0] + acc[rr][0]);
    ov[1] = (bf16_t)(bw[1] + acc[rr][1]);
    ov[2] = (bf16_t)(bw[2] + acc[rr][2]);
    ov[3] = (bf16_t)(bw[3] + acc[rr][3]);
    *(bf16x4*)(Wf + row * K_DIM + t * 4) = ov;
  }
}

// ---------------------------------------------------------------------------
// 256^2 8-phase GEMM (T1+T2+T3+T4+T5): out = Xh @ Wf^T + bias
// Requires hipFuncSetAttribute(MaxDynamicSharedMemorySize, 128 KB).
// ---------------------------------------------------------------------------
__global__ __launch_bounds__(512, 2) void gemm_qkv(
    const bf16_t* __restrict__ Xh,    // (16384, 1024) bf16
    const bf16_t* __restrict__ W,     // (3072, 1024)  bf16 row-major (N,K)
    const float*  __restrict__ bias,  // (3072,) fp32
    float* __restrict__ out)          // (16384, 3072) fp32
{
  extern __shared__ __align__(16) bf16_t sm[];  // 128 KB dynamic

  const int rawbid = blockIdx.x;
  const int bid = (rawbid & 7) * CHUNK_XCD + (rawbid >> 3);
  const int mt = bid / NTILE, nt = bid % NTILE;
  const int m0 = mt * BM, n0 = nt * BN;

  const int t = threadIdx.x;
  const int lane = t & 63;
  const int w = t >> 6;          // 0..7
  const int wm = w >> 2;         // 0..1 (M half)
  const int wn = w & 3;          // 0..3 (N quarter)

  // staging: thread t loads rows (t>>2), (t>>2)+128; 16B at pre-swizzled
  // k-slot sig = (t&3) ^ ((t>>3)&3)  (involution; (row>>1)&3 identical for
  // row and row+128). LDS dest linear: elem 8t within each region.
  const int srow = t >> 2;
  const int sig  = (t & 3) ^ ((t >> 3) & 3);
  const bf16_t* pA0 = Xh + (size_t)(m0 + srow) * K_DIM + sig * 8;
  const bf16_t* pA1 = pA0 + (size_t)128 * K_DIM;
  const bf16_t* pB0 = W  + (size_t)(n0 + srow) * K_DIM + sig * 8;
  const bf16_t* pB1 = pB0 + (size_t)128 * K_DIM;

  // fragment read offsets (elems, region-local), row stride 32 elems.
  // read slot = (lane>>4) ^ ((row>>1)&3): 16 consecutive rows cover all 8
  // 16B slots -> 2-way (free). Invariant across i*16 row steps.
  const int rA = wm * 128 + (lane & 15);
  const int rB = wn * 64  + (lane & 15);
  const int aoff = rA * 32 + (((lane >> 4) ^ ((rA >> 1) & 3)) * 8);
  const int boff = rB * 32 + (((lane >> 4) ^ ((rB >> 1) & 3)) * 8);

  f32x4 acc[8][4];
#pragma unroll
  for (int i = 0; i < 8; ++i)
#pragma unroll
    for (int j = 0; j < 4; ++j) acc[i][j] = (f32x4){0.f, 0.f, 0.f, 0.f};

#define STAGE(isB, c, kh, kb)                                              \
  do {                                                                     \
    const bf16_t* g0 = ((isB) ? pB0 : pA0) + (kb) + (kh) * 32;             \
    const bf16_t* g1 = ((isB) ? pB1 : pA1) + (kb) + (kh) * 32;             \
    bf16_t* l = sm + REGN(c, isB, kh) + w * 512;                           \
    gload_lds16(g0, l);                                                    \
    gload_lds16(g1, l + 4096);                                             \
  } while (0)

#define LOADA(c, kh)                                                       \
  {                                                                        \
    const bf16_t* base_ = sm + REGN(c, 0, kh) + aoff;                      \
    _Pragma("unroll") for (int i = 0; i < 8; ++i)                          \
        a[i] = *(const bf16x8*)(base_ + i * 512);                          \
  }

#define LOADB2(c, kh, j0)                                                  \
  {                                                                        \
    const bf16_t* base_ = sm + REGN(c, 1, kh) + boff;                      \
    b[j0]     = *(const bf16x8*)(base_ + (j0) * 512);                      \
    b[j0 + 1] = *(const bf16x8*)(base_ + ((j0) + 1) * 512);                \
  }

#define MFMA2(j0)                                                          \
  __builtin_amdgcn_s_setprio(1);                                           \
  _Pragma("unroll") for (int i = 0; i < 8; ++i) {                          \
    acc[i][j0] = __builtin_amdgcn_mfma_f32_16x16x32_bf16(                  \
        a[i], b[j0], acc[i][j0], 0, 0, 0);                                 \
    acc[i][(j0) + 1] = __builtin_amdgcn_mfma_f32_16x16x32_bf16(            \
        a[i], b[(j0) + 1], acc[i][(j0) + 1], 0, 0, 0);                     \
  }                                                                        \
  __builtin_amdgcn_s_setprio(0);

#define WAITV(n) asm volatile("s_waitcnt vmcnt(" #n ")" ::: "memory")
#define BARRIER()                                                          \
  __builtin_amdgcn_s_barrier();                                            \
  asm volatile("" ::: "memory")

  bf16x8 a[8], b[4];

  // prologue: fully stage tile 0 (4 half-tiles, 8 loads/thread)
  STAGE(0, 0, 0, 0);
  STAGE(1, 0, 0, 0);
  STAGE(0, 0, 1, 0);
  STAGE(1, 0, 1, 0);

  // main loop: tiles 0..14, staging tile tt+1 into the other buffer.
  // vmcnt retire order (per wave, in-order): WAITV(6) at q0 retires
  // A/B(kh0) of tile tt; at q2 retires A/B(kh1). Never drains to 0.
  for (int tt = 0; tt < 15; ++tt) {
    const int c = tt & 1, cn = c ^ 1;
    const int kb = (tt + 1) * BK;
    // q0: kh=0, n-frags 0,1
    STAGE(0, cn, 0, kb);
    WAITV(6);
    BARRIER();
    LOADA(c, 0);
    LOADB2(c, 0, 0);
    MFMA2(0);
    // q1: kh=0, n-frags 2,3 (reuse a[])
    STAGE(1, cn, 0, kb);
    LOADB2(c, 0, 2);
    MFMA2(2);
    // q2: kh=1, n-frags 0,1
    STAGE(0, cn, 1, kb);
    WAITV(6);
    BARRIER();
    LOADA(c, 1);
    LOADB2(c, 1, 0);
    MFMA2(0);
    // q3: kh=1, n-frags 2,3
    STAGE(1, cn, 1, kb);
    LOADB2(c, 1, 2);
    MFMA2(2);
  }

  // tile 15 (buffer 1), no more stages; drain 4 -> 0
  WAITV(4);
  BARRIER();
  LOADA(1, 0);
  LOADB2(1, 0, 0);
  MFMA2(0);
  LOADB2(1, 0, 2);
  MFMA2(2);
  WAITV(0);
  BARRIER();
  LOADA(1, 1);
  LOADB2(1, 1, 0);
  MFMA2(0);
  LOADB2(1, 1, 2);
  MFMA2(2);

  // epilogue: C/D layout col = lane&15, row = (lane>>4)*4 + reg
  const int colg = lane & 15;
  const int rq = (lane >> 4) * 4;
#pragma unroll
  for (int j = 0; j < 4; ++j) {
    const int n = n0 + wn * 64 + j * 16 + colg;
    const float bv = bias[n];
#pragma unroll
    for (int i = 0; i < 8; ++i) {
      const size_t mb = (size_t)(m0 + wm * 128 + i * 16 + rq);
#pragma unroll
      for (int r = 0; r < 4; ++r)
        out[(mb + r) * N_DIM + n] = acc[i][j][r] + bv;
    }
  }
#undef STAGE
#undef LOADA
#undef LOADB2
#undef MFMA2
#undef WAITV
#undef BARRIER
}

// ---------------------------------------------------------------------------
// Fallback GEMM: round-1-verified 128^2 m97-structure kernel (146 us gemm).
// PRECONV=true reads bf16 Xh; false reg-stages fp32 X.
// ---------------------------------------------------------------------------
#define FBM 128
#define FBN 128
#define FBK 32
template <bool PRECONV>
__global__ __launch_bounds__(256) void gemm128(
    const bf16_t* __restrict__ Xh,
    const float*  __restrict__ Xf,
    const bf16_t* __restrict__ W,
    const float*  __restrict__ bias,
    float* __restrict__ out)
{
  __shared__ bf16_t As[FBM * FBK];
  __shared__ bf16_t Bs[FBN * FBK];

  const int rawbid = blockIdx.x;
  const int nblk = (M_DIM / FBM) * (N_DIM / FBN);   // 3072
  const int bid = (rawbid & 7) * (nblk / 8) + (rawbid >> 3);
  const int nt = bid % (N_DIM / FBN);
  const int mt = bid / (N_DIM / FBN);
  const int m0 = mt * FBM;
  const int n0 = nt * FBN;

  const int t = threadIdx.x;
  const int lane = t & 63;
  const int w = t >> 6;
  const int wm = w >> 1;
  const int wn = w & 1;

  const int r0 = t >> 2;
  const int c0 = (t & 3) * 8;

  const bf16_t* gB0 = W + (size_t)(n0 + r0) * K_DIM + c0;
  const bf16_t* gB1 = gB0 + (size_t)64 * K_DIM;
  bf16_t* lA0 = As + r0 * FBK + c0;
  bf16_t* lA1 = As + (r0 + 64) * FBK + c0;
  bf16_t* lB0 = Bs + r0 * FBK + c0;
  bf16_t* lB1 = Bs + (r0 + 64) * FBK + c0;

  const bf16_t* gA0h = nullptr; const bf16_t* gA1h = nullptr;
  const float*  gA0f = nullptr; const float*  gA1f = nullptr;
  if constexpr (PRECONV) {
    gA0h = Xh + (size_t)(m0 + r0) * K_DIM + c0;
    gA1h = gA0h + (size_t)64 * K_DIM;
  } else {
    gA0f = Xf + (size_t)(m0 + r0) * K_DIM + c0;
    gA1f = gA0f + (size_t)64 * K_DIM;
  }

  f32x4 acc[4][4];
#pragma unroll
  for (int i = 0; i < 4; ++i)
#pragma unroll
    for (int j = 0; j < 4; ++j) acc[i][j] = (f32x4){0.f, 0.f, 0.f, 0.f};

  const int row_a = wm * 64 + (lane & 15);
  const int row_b = wn * 64 + (lane & 15);
  const int kb = (lane >> 4) * 8;

  for (int k0 = 0; k0 < K_DIM; k0 += FBK) {
    if constexpr (PRECONV) {
      gload_lds16(gA0h + k0, lA0);
      gload_lds16(gA1h + k0, lA1);
    } else {
      const f32x4 u0 = *(const f32x4*)(gA0f + k0);
      const f32x4 u1 = *(const f32x4*)(gA0f + k0 + 4);
      const f32x4 u2 = *(const f32x4*)(gA1f + k0);
      const f32x4 u3 = *(const f32x4*)(gA1f + k0 + 4);
      bf16x8 a0, a1;
#pragma unroll
      for (int c = 0; c < 4; ++c) {
        a0[c] = (bf16_t)u0[c]; a0[c + 4] = (bf16_t)u1[c];
        a1[c] = (bf16_t)u2[c]; a1[c + 4] = (bf16_t)u3[c];
      }
      *(bf16x8*)lA0 = a0;
      *(bf16x8*)lA1 = a1;
    }
    gload_lds16(gB0 + k0, lB0);
    gload_lds16(gB1 + k0, lB1);
    __syncthreads();

    bf16x8 a[4], b[4];
#pragma unroll
    for (int i = 0; i < 4; ++i)
      a[i] = *(const bf16x8*)(As + (row_a + i * 16) * FBK + kb);
#pragma unroll
    for (int j = 0; j < 4; ++j)
      b[j] = *(const bf16x8*)(Bs + (row_b + j * 16) * FBK + kb);

#pragma unroll
    for (int i = 0; i < 4; ++i)
#pragma unroll
      for (int j = 0; j < 4; ++j)
        acc[i][j] = __builtin_amdgcn_mfma_f32_16x16x32_bf16(a[i], b[j], acc[i][j], 0, 0, 0);

    __syncthreads();
  }

  const int colg = lane & 15;
  const int rq = (lane >> 4) * 4;
#pragma unroll
  for (int j = 0; j < 4; ++j) {
    const int n = n0 + wn * 64 + j * 16 + colg;
    const float bv = bias[n];
#pragma unroll
    for (int i = 0; i < 4; ++i) {
      const size_t mb = (size_t)(m0 + wm * 64 + i * 16 + rq);
#pragma unroll
      for (int r = 0; r < 4; ++r)
        out[(mb + r) * N_DIM + n] = acc[i][j][r] + bv;
    }
  }
}

extern "C" void kernel_launch(void* const* d_in, const int* in_sizes, int n_in,
                              void* d_out, int out_size, void* d_ws, size_t ws_size,
                              hipStream_t stream) {
  const float* x      = (const float*)d_in[0];
  const float* base_w = (const float*)d_in[1];
  const float* base_b = (const float*)d_in[2];
  const float* vA     = (const float*)d_in[3];
  const float* vB     = (const float*)d_in[4];
  const float* vd     = (const float*)d_in[5];
  const float* vb     = (const float*)d_in[6];
  float* out = (float*)d_out;

  const size_t xh_off   = 8u * 1024 * 1024;
  const size_t xh_bytes = (size_t)M_DIM * K_DIM * sizeof(bf16_t);

  bf16_t* Wf = (bf16_t*)d_ws;
  const bool preconv = ws_size >= xh_off + xh_bytes;
  bf16_t* Xh = preconv ? (bf16_t*)((char*)d_ws + xh_off) : nullptr;

  // Raise the dynamic-LDS limit for the 128 KB kernel exactly once.
  // hipFuncSetAttribute is a host-side, non-stream call (capture-safe).
  static int smem_ok = -1;
  if (smem_ok < 0) {
    hipError_t e = hipFuncSetAttribute(
        reinterpret_cast<const void*>(&gemm_qkv),
        hipFuncAttributeMaxDynamicSharedMemorySize, SMEM_BYTES);
    smem_ok = (e == hipSuccess) ? 1 : 0;
  }

  prep_all<<<preconv ? 8576 : 384, 256, 0, stream>>>(x, base_w, vA, vB, vd, vb, Wf, Xh);

  if (preconv && smem_ok == 1) {
    gemm_qkv<<<GRID_GEMM, 512, SMEM_BYTES, stream>>>(Xh, Wf, base_b, out);
  } else if (preconv) {
    gemm128<true><<<(M_DIM / FBM) * (N_DIM / FBN), 256, 0, stream>>>(
        Xh, nullptr, Wf, base_b, out);
  } else {
    gemm128<false><<<(M_DIM / FBM) * (N_DIM / FBN), 256, 0, stream>>>(
        nullptr, x, Wf, base_b, out);
  }
}